// Round 1
// baseline (4189.536 us; speedup 1.0000x reference)
//
#include <hip/hip_runtime.h>
#include <cstddef>
#include <cstdint>

// EdgeNet: out[e] = W3 @ elu(W2 @ elu(W0 @ concat(pos[dst]-pos[src], x[src], x[dst]) + b0) + b2) + b3
// Round 1: correct f32 baseline. Fused 3-layer MLP, 64 edges/block, transposed LDS activations.

#define N_EDGES_C 800000
#define D_FEAT_C  128
#define IN_CH_C   259
#define HID_C     256
#define OUT_CH_C  128
#define BM        64
#define PAD       65   // row stride (floats) for transposed LDS tiles; odd -> conflict-light

// dst[c*R + r] = src[r*C + c]; i indexes dst (coalesced writes)
__global__ void transpose_f32(const float* __restrict__ src,
                              float* __restrict__ dst, int R, int C) {
    int i = blockIdx.x * blockDim.x + threadIdx.x;
    if (i < R * C) {
        int c = i / R;
        int r = i - c * R;
        dst[i] = src[r * C + c];
    }
}

// Detect whether the edge_index buffer holds int64 (reference dtype) or int32
// (harness doc says "integer -> const int*"). Reading int32 data as u64 packs
// two indices; the high word is almost surely nonzero somewhere in 64 samples.
__global__ void detect_idx64(const void* __restrict__ ei_raw, int* __restrict__ flag) {
    if (blockIdx.x == 0 && threadIdx.x == 0) {
        const unsigned long long* p = (const unsigned long long*)ei_raw;
        int is64 = 1;
        for (int i = 0; i < 64; ++i) {
            if (p[i] >= (1ULL << 32)) { is64 = 0; break; }
        }
        *flag = is64;
    }
}

// One 256-wide layer: out_lds[j][m] = elu(sum_k in_lds[k][m] * wt[k][j] + b[j])
// wt is pre-transposed [K][256]. Thread (mc = t>>6, jg = t&63) owns 8 rows x 4 cols.
__device__ __forceinline__ void layer256(const float* __restrict__ wt,
                                         const float* __restrict__ b,
                                         const float* in_lds, float* out_lds,
                                         int K, int t) {
    const int jg = t & 63;
    const int mc = t >> 6;
    const float* wp = wt + jg * 4;
    const float4 bv = *(const float4*)&b[jg * 4];
    float acc[8][4];
#pragma unroll
    for (int i = 0; i < 8; ++i) {
        acc[i][0] = bv.x; acc[i][1] = bv.y; acc[i][2] = bv.z; acc[i][3] = bv.w;
    }
    const float* hbase = in_lds + mc * 8;
    float4 wv = *(const float4*)wp;            // 1-deep weight prefetch
    for (int k = 0; k < K; ++k) {
        float4 wn = wv;
        if (k + 1 < K) wn = *(const float4*)(wp + (size_t)(k + 1) * HID_C);
        float h[8];
#pragma unroll
        for (int i = 0; i < 8; ++i) h[i] = hbase[k * PAD + i];  // wave-broadcast LDS reads
#pragma unroll
        for (int i = 0; i < 8; ++i) {
            acc[i][0] += h[i] * wv.x;
            acc[i][1] += h[i] * wv.y;
            acc[i][2] += h[i] * wv.z;
            acc[i][3] += h[i] * wv.w;
        }
        wv = wn;
    }
#pragma unroll
    for (int i4 = 0; i4 < 4; ++i4) {
#pragma unroll
        for (int i = 0; i < 8; ++i) {
            float v = acc[i][i4];
            v = v > 0.0f ? v : expm1f(v);      // jax.nn.elu, alpha=1
            out_lds[(jg * 4 + i4) * PAD + mc * 8 + i] = v;
        }
    }
}

extern "C" __global__ void __launch_bounds__(512, 2)
edge_mlp_f32(const float* __restrict__ x, const void* __restrict__ ei_raw,
             const float* __restrict__ pos, const int* __restrict__ idx64_flag,
             const float* __restrict__ wt0, const float* __restrict__ b0,
             const float* __restrict__ wt2, const float* __restrict__ b2,
             const float* __restrict__ wt3, const float* __restrict__ b3,
             float* __restrict__ out) {
    __shared__ float buf1[IN_CH_C * PAD];   // inpT [259][PAD], reused as h2T [256][PAD]
    __shared__ float buf2[HID_C * PAD];     // h1T  [256][PAD]
    __shared__ int s_src[BM], s_dst[BM];

    const int t = threadIdx.x;
    const int e0 = blockIdx.x * BM;

    if (t < BM) {
        int s, d;
        if (*idx64_flag) {
            const long long* e = (const long long*)ei_raw;
            s = (int)e[e0 + t];
            d = (int)e[N_EDGES_C + e0 + t];
        } else {
            const int* e = (const int*)ei_raw;
            s = e[e0 + t];
            d = e[N_EDGES_C + e0 + t];
        }
        s_src[t] = s;
        s_dst[t] = d;
    }
    __syncthreads();

    // stage edge_attr = pos[dst] - pos[src] into rows 0..2
    if (t < BM) {
        const int s = s_src[t], d = s_dst[t];
#pragma unroll
        for (int i = 0; i < 3; ++i)
            buf1[i * PAD + t] = pos[d * 3 + i] - pos[s * 3 + i];
    }
    // gather x[src] -> rows 3..130, x[dst] -> rows 131..258 (transposed)
    {
        const int l = t & 31, grp = t >> 5;
#pragma unroll
        for (int r = 0; r < 4; ++r) {
            const int m = grp + r * 16;
            const int s = s_src[m], d = s_dst[m];
            const float4 xi = *(const float4*)&x[(size_t)s * D_FEAT_C + l * 4];
            const float4 xj = *(const float4*)&x[(size_t)d * D_FEAT_C + l * 4];
            buf1[(3 + l * 4 + 0) * PAD + m] = xi.x;
            buf1[(3 + l * 4 + 1) * PAD + m] = xi.y;
            buf1[(3 + l * 4 + 2) * PAD + m] = xi.z;
            buf1[(3 + l * 4 + 3) * PAD + m] = xi.w;
            buf1[(131 + l * 4 + 0) * PAD + m] = xj.x;
            buf1[(131 + l * 4 + 1) * PAD + m] = xj.y;
            buf1[(131 + l * 4 + 2) * PAD + m] = xj.z;
            buf1[(131 + l * 4 + 3) * PAD + m] = xj.w;
        }
    }
    __syncthreads();

    layer256(wt0, b0, buf1, buf2, IN_CH_C, t);   // layer 0: K=259, reads buf1 writes buf2
    __syncthreads();
    layer256(wt2, b2, buf2, buf1, HID_C, t);     // layer 1: K=256, reads buf2 writes buf1
    __syncthreads();

    // layer 2: K=256, 128 output cols, write global. Thread (mc = t>>5, jg = t&31): 4 rows x 4 cols.
    {
        const int jg = t & 31;
        const int mc = t >> 5;
        const float* wp = wt3 + jg * 4;
        const float4 bv = *(const float4*)&b3[jg * 4];
        float acc[4][4];
#pragma unroll
        for (int i = 0; i < 4; ++i) {
            acc[i][0] = bv.x; acc[i][1] = bv.y; acc[i][2] = bv.z; acc[i][3] = bv.w;
        }
        const float* hbase = buf1 + mc * 4;
        float4 wv = *(const float4*)wp;
        for (int k = 0; k < HID_C; ++k) {
            float4 wn = wv;
            if (k + 1 < HID_C) wn = *(const float4*)(wp + (size_t)(k + 1) * OUT_CH_C);
            float h[4];
#pragma unroll
            for (int i = 0; i < 4; ++i) h[i] = hbase[k * PAD + i];
#pragma unroll
            for (int i = 0; i < 4; ++i) {
                acc[i][0] += h[i] * wv.x;
                acc[i][1] += h[i] * wv.y;
                acc[i][2] += h[i] * wv.z;
                acc[i][3] += h[i] * wv.w;
            }
            wv = wn;
        }
#pragma unroll
        for (int i = 0; i < 4; ++i) {
            float4 o;
            o.x = acc[i][0]; o.y = acc[i][1]; o.z = acc[i][2]; o.w = acc[i][3];
            *(float4*)&out[(size_t)(e0 + mc * 4 + i) * OUT_CH_C + jg * 4] = o;
        }
    }
}

extern "C" void kernel_launch(void* const* d_in, const int* in_sizes, int n_in,
                              void* d_out, int out_size, void* d_ws, size_t ws_size,
                              hipStream_t stream) {
    const float* x   = (const float*)d_in[0];
    const void*  ei  = d_in[1];               // int32 or int64, detected on device
    const float* pos = (const float*)d_in[2];
    const float* W0  = (const float*)d_in[3];
    const float* b0  = (const float*)d_in[4];
    const float* W2  = (const float*)d_in[5];
    const float* b2  = (const float*)d_in[6];
    const float* W3  = (const float*)d_in[7];
    const float* b3  = (const float*)d_in[8];
    float* out = (float*)d_out;

    // ws layout: transposed weights + idx-dtype flag (~659 KB total)
    float* wt0 = (float*)d_ws;                 // [259][256]
    float* wt2 = wt0 + IN_CH_C * HID_C;        // [256][256]
    float* wt3 = wt2 + HID_C * HID_C;          // [256][128]
    int*   flag = (int*)(wt3 + HID_C * OUT_CH_C);

    detect_idx64<<<1, 64, 0, stream>>>(ei, flag);

    int n0 = HID_C * IN_CH_C;
    transpose_f32<<<(n0 + 255) / 256, 256, 0, stream>>>(W0, wt0, HID_C, IN_CH_C);
    int n2 = HID_C * HID_C;
    transpose_f32<<<(n2 + 255) / 256, 256, 0, stream>>>(W2, wt2, HID_C, HID_C);
    int n3 = OUT_CH_C * HID_C;
    transpose_f32<<<(n3 + 255) / 256, 256, 0, stream>>>(W3, wt3, OUT_CH_C, HID_C);

    edge_mlp_f32<<<N_EDGES_C / BM, 512, 0, stream>>>(
        x, ei, pos, flag, wt0, b0, wt2, b2, wt3, b3, out);
}

// Round 2
// 588.690 us; speedup vs baseline: 7.1167x; 7.1167x over previous
//
#include <hip/hip_runtime.h>
#include <cstddef>
#include <cstdint>

// EdgeNet bf16-MFMA pipeline:
//   precompute per-node A[n] = x[n]@W0i^T - pos[n]@W0e^T + b0,  B[n] = x[n]@W0j^T + pos[n]@W0e^T
//   per edge: h1 = elu(A[src] + B[dst])        (gather+add, layer0 GEMM eliminated)
//             h2 = elu(h1 @ W2^T + b2)          (bf16 MFMA, swapped D = W2*h1^T)
//             out = h2 @ W3^T + b3              (bf16 MFMA)

#define N_NODES_C 50000
#define N_EDGES_C 800000
#define D_FEAT_C  128
#define IN_CH_C   259
#define HID_C     256
#define OUT_CH_C  128

typedef unsigned short u16;
typedef short bf16x8 __attribute__((ext_vector_type(8)));
typedef float f32x4 __attribute__((ext_vector_type(4)));

__device__ __forceinline__ u16 f2bf(float f) {
    union { float f; unsigned u; } v; v.f = f;
    unsigned u = v.u;
    return (u16)((u + 0x7fffu + ((u >> 16) & 1u)) >> 16);   // RNE
}
__device__ __forceinline__ float bf2f_lo(unsigned u) {
    union { unsigned u; float f; } v; v.u = u << 16; return v.f;
}
__device__ __forceinline__ float bf2f_hi(unsigned u) {
    union { unsigned u; float f; } v; v.u = u & 0xFFFF0000u; return v.f;
}
__device__ __forceinline__ float elu1(float x) {
    return x > 0.0f ? x : (__expf(x) - 1.0f);
}
__device__ __forceinline__ unsigned addelu2(unsigned a, unsigned b) {
    float s0 = elu1(bf2f_lo(a) + bf2f_lo(b));
    float s1 = elu1(bf2f_hi(a) + bf2f_hi(b));
    return (unsigned)f2bf(s0) | ((unsigned)f2bf(s1) << 16);
}

__global__ void detect_idx64(const void* __restrict__ ei_raw, int* __restrict__ flag) {
    if (blockIdx.x == 0 && threadIdx.x == 0) {
        const unsigned long long* p = (const unsigned long long*)ei_raw;
        int is64 = 1;
        for (int i = 0; i < 64; ++i)
            if (p[i] >= (1ULL << 32)) { is64 = 0; break; }
        *flag = is64;
    }
}

// Build WAB[512][160] (K = 128 x | 3 pos | 29 pad), W2b[256][256], W3b[128][256] in bf16.
__global__ void prep_weights(const float* __restrict__ W0, const float* __restrict__ W2,
                             const float* __restrict__ W3, u16* __restrict__ WAB,
                             u16* __restrict__ W2b, u16* __restrict__ W3b) {
    int i = blockIdx.x * blockDim.x + threadIdx.x;
    const int nwab = 512 * 160, nw2 = 256 * 256, nw3 = 128 * 256;
    if (i < nwab) {
        int j = i / 160, k = i - j * 160;
        float v = 0.f;
        if (j < 256) {                       // A-weights (src role)
            if (k < 128) v = W0[j * IN_CH_C + 3 + k];
            else if (k < 131) v = -W0[j * IN_CH_C + (k - 128)];
        } else {                             // B-weights (dst role)
            int j2 = j - 256;
            if (k < 128) v = W0[j2 * IN_CH_C + 131 + k];
            else if (k < 131) v = W0[j2 * IN_CH_C + (k - 128)];
        }
        WAB[i] = f2bf(v);
    } else if (i < nwab + nw2) {
        int q = i - nwab; W2b[q] = f2bf(W2[q]);
    } else if (i < nwab + nw2 + nw3) {
        int q = i - nwab - nw2; W3b[q] = f2bf(W3[q]);
    }
}

// AB[n][0..255] = A[n] (+b0), AB[n][256..511] = B[n].  M=50000, N=512, K=160.
extern "C" __global__ void __launch_bounds__(512, 2)
node_gemm(const float* __restrict__ x, const float* __restrict__ pos,
          const u16* __restrict__ WAB, const float* __restrict__ b0,
          u16* __restrict__ AB) {
    __shared__ u16 tile[128 * 168];          // [m][k] row stride 168 (336B, 16B-aligned)
    const int t = threadIdx.x;
    const int row0 = blockIdx.x * 128;
    for (int idx = t; idx < 128 * 80; idx += 512) {
        int m = idx / 80, wq = idx - m * 80;
        int k = wq * 2, n = row0 + m;
        float f0 = 0.f, f1 = 0.f;
        if (n < N_NODES_C) {
            f0 = (k < 128) ? x[(size_t)n * 128 + k] : (k < 131 ? pos[(size_t)n * 3 + k - 128] : 0.f);
            int k1 = k + 1;
            f1 = (k1 < 128) ? x[(size_t)n * 128 + k1] : (k1 < 131 ? pos[(size_t)n * 3 + k1 - 128] : 0.f);
        }
        *(unsigned*)&tile[m * 168 + k] = (unsigned)f2bf(f0) | ((unsigned)f2bf(f1) << 16);
    }
    __syncthreads();
    const int w = t >> 6, l = t & 63, lr = l & 15, hi = l >> 4;
    for (int mc = 0; mc < 2; ++mc) {
        f32x4 acc[4][4];                     // [ji][mi]; D[j][m]
#pragma unroll
        for (int ji = 0; ji < 4; ++ji)
#pragma unroll
            for (int mi = 0; mi < 4; ++mi)
                acc[ji][mi] = (f32x4){0.f, 0.f, 0.f, 0.f};
#pragma unroll
        for (int kk = 0; kk < 5; ++kk) {
            bf16x8 af[4], bfr[4];
#pragma unroll
            for (int ji = 0; ji < 4; ++ji)
                af[ji] = *(const bf16x8*)&WAB[(size_t)(w * 64 + ji * 16 + lr) * 160 + kk * 32 + hi * 8];
#pragma unroll
            for (int mi = 0; mi < 4; ++mi)
                bfr[mi] = *(const bf16x8*)&tile[(mc * 64 + mi * 16 + lr) * 168 + kk * 32 + hi * 8];
#pragma unroll
            for (int ji = 0; ji < 4; ++ji)
#pragma unroll
                for (int mi = 0; mi < 4; ++mi)
                    acc[ji][mi] = __builtin_amdgcn_mfma_f32_16x16x32_bf16(af[ji], bfr[mi], acc[ji][mi], 0, 0, 0);
        }
#pragma unroll
        for (int ji = 0; ji < 4; ++ji) {
            int j0 = w * 64 + ji * 16 + hi * 4;     // 4 consecutive j per lane
            float4 bb = make_float4(0.f, 0.f, 0.f, 0.f);
            if (j0 < 256) bb = *(const float4*)&b0[j0];   // bias folded into A half only
#pragma unroll
            for (int mi = 0; mi < 4; ++mi) {
                int nn = row0 + mc * 64 + mi * 16 + lr;
                if (nn < N_NODES_C) {
                    f32x4 v = acc[ji][mi];
                    uint2 pr;
                    pr.x = (unsigned)f2bf(v[0] + bb.x) | ((unsigned)f2bf(v[1] + bb.y) << 16);
                    pr.y = (unsigned)f2bf(v[2] + bb.z) | ((unsigned)f2bf(v[3] + bb.w) << 16);
                    *(uint2*)&AB[(size_t)nn * 512 + j0] = pr;
                }
            }
        }
    }
}

// Main edge kernel: 128 edges/block, 8 waves.
extern "C" __global__ void __launch_bounds__(512, 2)
edge_mlp_bf16(const u16* __restrict__ AB, const void* __restrict__ ei_raw,
              const int* __restrict__ idx64_flag,
              const u16* __restrict__ W2b, const float* __restrict__ b2,
              const u16* __restrict__ W3b, const float* __restrict__ b3,
              float* __restrict__ out) {
    __shared__ u16 hbuf[128 * 264];          // h1 then h2, row stride 264 (528B)
    __shared__ int s_src[128], s_dst[128];
    const int t = threadIdx.x;
    const size_t e0 = (size_t)blockIdx.x * 128;

    if (t < 128) {
        int s, d;
        if (*idx64_flag) {
            const long long* e = (const long long*)ei_raw;
            s = (int)e[e0 + t]; d = (int)e[N_EDGES_C + e0 + t];
        } else {
            const int* e = (const int*)ei_raw;
            s = e[e0 + t]; d = e[N_EDGES_C + e0 + t];
        }
        s_src[t] = s; s_dst[t] = d;
    }
    __syncthreads();

    // ---- phase 0: h1[m][k] = elu(A[src][k] + B[dst][k]) ----
    {
        const int m = t >> 2, p = t & 3;
        const u16* ra = AB + (size_t)s_src[m] * 512;         // A half
        const u16* rb = AB + (size_t)s_dst[m] * 512 + 256;   // B half
        uint4 a[8], b[8];
#pragma unroll
        for (int i = 0; i < 8; ++i) {
            int k0 = p * 8 + i * 32;
            a[i] = *(const uint4*)(ra + k0);
            b[i] = *(const uint4*)(rb + k0);
        }
#pragma unroll
        for (int i = 0; i < 8; ++i) {
            int k0 = p * 8 + i * 32;
            uint4 r;
            r.x = addelu2(a[i].x, b[i].x);
            r.y = addelu2(a[i].y, b[i].y);
            r.z = addelu2(a[i].z, b[i].z);
            r.w = addelu2(a[i].w, b[i].w);
            *(uint4*)&hbuf[m * 264 + k0] = r;
        }
    }
    __syncthreads();

    const int w = t >> 6, l = t & 63, lr = l & 15, hi = l >> 4;

    // ---- layer 1 (swapped): D[j][m] = W2[j][:] . h1[m][:] ----
    const int wj = w & 3, wm = w >> 2;
    f32x4 acc[4][4];                          // [ji][mi]
#pragma unroll
    for (int ji = 0; ji < 4; ++ji) {
        const float4 bb = *(const float4*)&b2[wj * 64 + ji * 16 + hi * 4];
#pragma unroll
        for (int mi = 0; mi < 4; ++mi)
            acc[ji][mi] = (f32x4){bb.x, bb.y, bb.z, bb.w};
    }
#pragma unroll
    for (int kk = 0; kk < 8; ++kk) {
        bf16x8 af[4], bfr[4];
#pragma unroll
        for (int ji = 0; ji < 4; ++ji)
            af[ji] = *(const bf16x8*)&W2b[(size_t)(wj * 64 + ji * 16 + lr) * 256 + kk * 32 + hi * 8];
#pragma unroll
        for (int mi = 0; mi < 4; ++mi)
            bfr[mi] = *(const bf16x8*)&hbuf[(wm * 64 + mi * 16 + lr) * 264 + kk * 32 + hi * 8];
#pragma unroll
        for (int ji = 0; ji < 4; ++ji)
#pragma unroll
            for (int mi = 0; mi < 4; ++mi)
                acc[ji][mi] = __builtin_amdgcn_mfma_f32_16x16x32_bf16(af[ji], bfr[mi], acc[ji][mi], 0, 0, 0);
    }
    __syncthreads();                          // everyone done reading h1

    // epilogue: h2[m][j] = elu(D[j][m]); lane holds 4 consecutive j -> b64 write
#pragma unroll
    for (int ji = 0; ji < 4; ++ji) {
        int j0 = wj * 64 + ji * 16 + hi * 4;
#pragma unroll
        for (int mi = 0; mi < 4; ++mi) {
            int m = wm * 64 + mi * 16 + lr;
            f32x4 v = acc[ji][mi];
            uint2 pr;
            pr.x = (unsigned)f2bf(elu1(v[0])) | ((unsigned)f2bf(elu1(v[1])) << 16);
            pr.y = (unsigned)f2bf(elu1(v[2])) | ((unsigned)f2bf(elu1(v[3])) << 16);
            *(uint2*)&hbuf[m * 264 + j0] = pr;
        }
    }
    __syncthreads();

    // ---- layer 2: out[m][o] = h2[m][:] . W3[o][:] + b3 ----
    const int wm3 = w & 1, wo = w >> 1;
    f32x4 acc2[4][2];                         // [mi][oi]; D[m][o]
#pragma unroll
    for (int oi = 0; oi < 2; ++oi) {
        float bbv = b3[wo * 32 + oi * 16 + lr];
#pragma unroll
        for (int mi = 0; mi < 4; ++mi)
            acc2[mi][oi] = (f32x4){bbv, bbv, bbv, bbv};
    }
#pragma unroll
    for (int kk = 0; kk < 8; ++kk) {
        bf16x8 af[4], bfr[2];
#pragma unroll
        for (int mi = 0; mi < 4; ++mi)
            af[mi] = *(const bf16x8*)&hbuf[(wm3 * 64 + mi * 16 + lr) * 264 + kk * 32 + hi * 8];
#pragma unroll
        for (int oi = 0; oi < 2; ++oi)
            bfr[oi] = *(const bf16x8*)&W3b[(size_t)(wo * 32 + oi * 16 + lr) * 256 + kk * 32 + hi * 8];
#pragma unroll
        for (int mi = 0; mi < 4; ++mi)
#pragma unroll
            for (int oi = 0; oi < 2; ++oi)
                acc2[mi][oi] = __builtin_amdgcn_mfma_f32_16x16x32_bf16(af[mi], bfr[oi], acc2[mi][oi], 0, 0, 0);
    }
#pragma unroll
    for (int mi = 0; mi < 4; ++mi)
#pragma unroll
        for (int oi = 0; oi < 2; ++oi) {
            int o = wo * 32 + oi * 16 + lr;
            int mbase = wm3 * 64 + mi * 16 + hi * 4;
            f32x4 v = acc2[mi][oi];
#pragma unroll
            for (int r = 0; r < 4; ++r)
                out[(e0 + mbase + r) * 128 + o] = v[r];
        }
}

// ---------------- round-1 f32 fallback (ws too small) ----------------
#define BM 64
#define PAD 65
__global__ void transpose_f32(const float* __restrict__ src, float* __restrict__ dst, int R, int C) {
    int i = blockIdx.x * blockDim.x + threadIdx.x;
    if (i < R * C) { int c = i / R; int r = i - c * R; dst[i] = src[r * C + c]; }
}
__device__ __forceinline__ void layer256(const float* __restrict__ wt, const float* __restrict__ b,
                                         const float* in_lds, float* out_lds, int K, int t) {
    const int jg = t & 63, mc = t >> 6;
    const float* wp = wt + jg * 4;
    const float4 bv = *(const float4*)&b[jg * 4];
    float acc[8][4];
#pragma unroll
    for (int i = 0; i < 8; ++i) { acc[i][0] = bv.x; acc[i][1] = bv.y; acc[i][2] = bv.z; acc[i][3] = bv.w; }
    const float* hbase = in_lds + mc * 8;
    float4 wv = *(const float4*)wp;
    for (int k = 0; k < K; ++k) {
        float4 wn = wv;
        if (k + 1 < K) wn = *(const float4*)(wp + (size_t)(k + 1) * HID_C);
        float h[8];
#pragma unroll
        for (int i = 0; i < 8; ++i) h[i] = hbase[k * PAD + i];
#pragma unroll
        for (int i = 0; i < 8; ++i) {
            acc[i][0] += h[i] * wv.x; acc[i][1] += h[i] * wv.y;
            acc[i][2] += h[i] * wv.z; acc[i][3] += h[i] * wv.w;
        }
        wv = wn;
    }
#pragma unroll
    for (int i4 = 0; i4 < 4; ++i4)
#pragma unroll
        for (int i = 0; i < 8; ++i) {
            float v = acc[i][i4];
            v = v > 0.0f ? v : expm1f(v);
            out_lds[(jg * 4 + i4) * PAD + mc * 8 + i] = v;
        }
}
extern "C" __global__ void __launch_bounds__(512, 2)
edge_mlp_f32(const float* __restrict__ x, const void* __restrict__ ei_raw,
             const float* __restrict__ pos, const int* __restrict__ idx64_flag,
             const float* __restrict__ wt0, const float* __restrict__ b0,
             const float* __restrict__ wt2, const float* __restrict__ b2,
             const float* __restrict__ wt3, const float* __restrict__ b3,
             float* __restrict__ out) {
    __shared__ float buf1[IN_CH_C * PAD];
    __shared__ float buf2[HID_C * PAD];
    __shared__ int s_src[BM], s_dst[BM];
    const int t = threadIdx.x;
    const int e0 = blockIdx.x * BM;
    if (t < BM) {
        int s, d;
        if (*idx64_flag) {
            const long long* e = (const long long*)ei_raw;
            s = (int)e[e0 + t]; d = (int)e[N_EDGES_C + e0 + t];
        } else {
            const int* e = (const int*)ei_raw;
            s = e[e0 + t]; d = e[N_EDGES_C + e0 + t];
        }
        s_src[t] = s; s_dst[t] = d;
    }
    __syncthreads();
    if (t < BM) {
        const int s = s_src[t], d = s_dst[t];
#pragma unroll
        for (int i = 0; i < 3; ++i)
            buf1[i * PAD + t] = pos[d * 3 + i] - pos[s * 3 + i];
    }
    {
        const int l = t & 31, grp = t >> 5;
#pragma unroll
        for (int r = 0; r < 4; ++r) {
            const int m = grp + r * 16;
            const int s = s_src[m], d = s_dst[m];
            const float4 xi = *(const float4*)&x[(size_t)s * D_FEAT_C + l * 4];
            const float4 xj = *(const float4*)&x[(size_t)d * D_FEAT_C + l * 4];
            buf1[(3 + l * 4 + 0) * PAD + m] = xi.x; buf1[(3 + l * 4 + 1) * PAD + m] = xi.y;
            buf1[(3 + l * 4 + 2) * PAD + m] = xi.z; buf1[(3 + l * 4 + 3) * PAD + m] = xi.w;
            buf1[(131 + l * 4 + 0) * PAD + m] = xj.x; buf1[(131 + l * 4 + 1) * PAD + m] = xj.y;
            buf1[(131 + l * 4 + 2) * PAD + m] = xj.z; buf1[(131 + l * 4 + 3) * PAD + m] = xj.w;
        }
    }
    __syncthreads();
    layer256(wt0, b0, buf1, buf2, IN_CH_C, t);
    __syncthreads();
    layer256(wt2, b2, buf2, buf1, HID_C, t);
    __syncthreads();
    {
        const int jg = t & 31, mc = t >> 5;
        const float* wp = wt3 + jg * 4;
        const float4 bv = *(const float4*)&b3[jg * 4];
        float acc[4][4];
#pragma unroll
        for (int i = 0; i < 4; ++i) { acc[i][0] = bv.x; acc[i][1] = bv.y; acc[i][2] = bv.z; acc[i][3] = bv.w; }
        const float* hbase = buf1 + mc * 4;
        float4 wv = *(const float4*)wp;
        for (int k = 0; k < HID_C; ++k) {
            float4 wn = wv;
            if (k + 1 < HID_C) wn = *(const float4*)(wp + (size_t)(k + 1) * OUT_CH_C);
            float h[4];
#pragma unroll
            for (int i = 0; i < 4; ++i) h[i] = hbase[k * PAD + i];
#pragma unroll
            for (int i = 0; i < 4; ++i) {
                acc[i][0] += h[i] * wv.x; acc[i][1] += h[i] * wv.y;
                acc[i][2] += h[i] * wv.z; acc[i][3] += h[i] * wv.w;
            }
            wv = wn;
        }
#pragma unroll
        for (int i = 0; i < 4; ++i) {
            float4 o;
            o.x = acc[i][0]; o.y = acc[i][1]; o.z = acc[i][2]; o.w = acc[i][3];
            *(float4*)&out[(size_t)(e0 + mc * 4 + i) * OUT_CH_C + jg * 4] = o;
        }
    }
}

extern "C" void kernel_launch(void* const* d_in, const int* in_sizes, int n_in,
                              void* d_out, int out_size, void* d_ws, size_t ws_size,
                              hipStream_t stream) {
    const float* x   = (const float*)d_in[0];
    const void*  ei  = d_in[1];
    const float* pos = (const float*)d_in[2];
    const float* W0  = (const float*)d_in[3];
    const float* b0  = (const float*)d_in[4];
    const float* W2  = (const float*)d_in[5];
    const float* b2  = (const float*)d_in[6];
    const float* W3  = (const float*)d_in[7];
    const float* b3  = (const float*)d_in[8];
    float* out = (float*)d_out;

    const size_t need = (size_t)N_NODES_C * 512 * 2 + (size_t)512 * 160 * 2
                      + (size_t)256 * 256 * 2 + (size_t)128 * 256 * 2 + 16;
    if (ws_size >= need) {
        u16* AB  = (u16*)d_ws;                         // [50000][512]
        u16* WAB = AB + (size_t)N_NODES_C * 512;       // [512][160]
        u16* W2b = WAB + 512 * 160;                    // [256][256]
        u16* W3b = W2b + 256 * 256;                    // [128][256]
        int* flag = (int*)(W3b + 128 * 256);

        detect_idx64<<<1, 64, 0, stream>>>(ei, flag);
        prep_weights<<<704, 256, 0, stream>>>(W0, W2, W3, WAB, W2b, W3b);
        node_gemm<<<391, 512, 0, stream>>>(x, pos, WAB, b0, AB);
        edge_mlp_bf16<<<N_EDGES_C / 128, 512, 0, stream>>>(AB, ei, flag, W2b, b2, W3b, b3, out);
    } else {
        float* wt0 = (float*)d_ws;
        float* wt2 = wt0 + IN_CH_C * HID_C;
        float* wt3 = wt2 + HID_C * HID_C;
        int*   flag = (int*)(wt3 + HID_C * OUT_CH_C);

        detect_idx64<<<1, 64, 0, stream>>>(ei, flag);
        int n0 = HID_C * IN_CH_C;
        transpose_f32<<<(n0 + 255) / 256, 256, 0, stream>>>(W0, wt0, HID_C, IN_CH_C);
        int n2 = HID_C * HID_C;
        transpose_f32<<<(n2 + 255) / 256, 256, 0, stream>>>(W2, wt2, HID_C, HID_C);
        int n3 = OUT_CH_C * HID_C;
        transpose_f32<<<(n3 + 255) / 256, 256, 0, stream>>>(W3, wt3, OUT_CH_C, HID_C);
        edge_mlp_f32<<<N_EDGES_C / BM, 512, 0, stream>>>(
            x, ei, pos, flag, wt0, b0, wt2, b2, wt3, b3, out);
    }
}